// Round 1
// baseline (407.244 us; speedup 1.0000x reference)
//
#include <hip/hip_runtime.h>
#include <stdint.h>

#define N_NODES 50000
#define N_EDGES 600000
#define M_PAD   50048   // padded rows for GEMM tiles (multiple of 64)

typedef __bf16 bf16x8 __attribute__((ext_vector_type(8)));
typedef float  f32x4  __attribute__((ext_vector_type(4)));

__device__ __forceinline__ unsigned short f2bf(float f) {
  union { float f; unsigned u; } v; v.f = f;
  unsigned r = v.u + 0x7FFF + ((v.u >> 16) & 1);  // round-to-nearest-even
  return (unsigned short)(r >> 16);
}

__global__ void zero_kernel(int* __restrict__ p, int n) {
  int i = blockIdx.x * blockDim.x + threadIdx.x;
  if (i < n) p[i] = 0;
}

__global__ void hist_kernel(const int* __restrict__ dst, int* __restrict__ cnt, int e) {
  int i = blockIdx.x * blockDim.x + threadIdx.x;
  if (i < e) atomicAdd(&cnt[dst[i]], 1);
}

// blockIdx.x = relation (0/1). Single-block sequential-chunk scan: exclusive
// prefix over 50000 counts -> off[0..N], plus a cursor copy for the scatter.
__global__ void scan_kernel(const int* __restrict__ cnt1, const int* __restrict__ cnt2,
                            int* __restrict__ off1, int* __restrict__ off2,
                            int* __restrict__ cur1, int* __restrict__ cur2, int n) {
  const int* cnt = (blockIdx.x == 0) ? cnt1 : cnt2;
  int* off = (blockIdx.x == 0) ? off1 : off2;
  int* cur = (blockIdx.x == 0) ? cur1 : cur2;
  __shared__ int buf[1024];
  __shared__ int carry_s;
  if (threadIdx.x == 0) carry_s = 0;
  __syncthreads();
  for (int base = 0; base < n; base += 1024) {
    int i = base + threadIdx.x;
    int v = (i < n) ? cnt[i] : 0;
    buf[threadIdx.x] = v;
    __syncthreads();
    for (int d = 1; d < 1024; d <<= 1) {
      int t = (threadIdx.x >= d) ? buf[threadIdx.x - d] : 0;
      __syncthreads();
      buf[threadIdx.x] += t;
      __syncthreads();
    }
    int carry = carry_s;              // stable: last write was before a barrier
    int exc = carry + buf[threadIdx.x] - v;
    if (i < n) { off[i] = exc; cur[i] = exc; }
    int tot = buf[1023];
    __syncthreads();
    if (threadIdx.x == 0) carry_s = carry + tot;
    __syncthreads();
  }
  if (threadIdx.x == 0) off[n] = carry_s;
}

__global__ void fill_kernel(const int* __restrict__ src, const int* __restrict__ dst,
                            int* __restrict__ cur, int* __restrict__ csr, int e) {
  int i = blockIdx.x * blockDim.x + threadIdx.x;
  if (i < e) {
    int d = dst[i];
    int p = atomicAdd(&cur[d], 1);
    csr[p] = src[i];
  }
}

// One wave per node; lane owns channels {2*lane, 2*lane+1}. Sequential reduce
// over the node's CSR edge list -> mean/max/min/sum written bf16 [N][512].
__global__ void aggregate_kernel(const float* __restrict__ x, const int* __restrict__ csr,
                                 const int* __restrict__ off, unsigned short* __restrict__ s) {
  int wid = blockIdx.x * 4 + (threadIdx.x >> 6);
  int lane = threadIdx.x & 63;
  if (wid >= N_NODES) return;
  int beg = off[wid], end = off[wid + 1];
  float s0 = 0.f, s1v = 0.f;
  float mx0 = -3.0e38f, mx1 = -3.0e38f;
  float mn0 = 3.0e38f, mn1 = 3.0e38f;
  for (int e = beg; e < end; ++e) {
    int sr = csr[e];
    float2 v = *((const float2*)(x + (size_t)sr * 128) + lane);
    s0 += v.x; s1v += v.y;
    mx0 = fmaxf(mx0, v.x); mx1 = fmaxf(mx1, v.y);
    mn0 = fminf(mn0, v.x); mn1 = fminf(mn1, v.y);
  }
  int deg = end - beg;
  float inv = (deg > 0) ? (1.0f / (float)deg) : 0.0f;
  float me0 = s0 * inv, me1 = s1v * inv;
  if (deg == 0) { mx0 = mx1 = mn0 = mn1 = 0.f; }
  unsigned short* row = s + (size_t)wid * 512;
  *(ushort2*)(row +   0 + 2 * lane) = make_ushort2(f2bf(me0), f2bf(me1));
  *(ushort2*)(row + 128 + 2 * lane) = make_ushort2(f2bf(mx0), f2bf(mx1));
  *(ushort2*)(row + 256 + 2 * lane) = make_ushort2(f2bf(mn0), f2bf(mn1));
  *(ushort2*)(row + 384 + 2 * lane) = make_ushort2(f2bf(s0),  f2bf(s1v));
}

__global__ void convx_kernel(const float* __restrict__ x, unsigned short* __restrict__ xb) {
  int i = blockIdx.x * blockDim.x + threadIdx.x;  // float2 index
  if (i < N_NODES * 64) {
    float2 v = ((const float2*)x)[i];
    ((ushort2*)xb)[i] = make_ushort2(f2bf(v.x), f2bf(v.y));
  }
}

// B matrix [n=128][k=1152] bf16: k<128 -> W1_r1+W1_r2 ; 128..640 -> W2_r1 ; rest W2_r2
__global__ void buildB_kernel(const float* __restrict__ W1a, const float* __restrict__ W2a,
                              const float* __restrict__ W1b, const float* __restrict__ W2b,
                              unsigned short* __restrict__ Bm) {
  int i = blockIdx.x * blockDim.x + threadIdx.x;
  if (i >= 128 * 1152) return;
  int n = i / 1152, k = i % 1152;
  float v;
  if (k < 128)      v = W1a[n * 128 + k] + W1b[n * 128 + k];
  else if (k < 640) v = W2a[n * 512 + (k - 128)];
  else              v = W2b[n * 512 + (k - 640)];
  Bm[i] = f2bf(v);
}

__device__ __forceinline__ void gload16(void* lds, const void* g) {
  __builtin_amdgcn_global_load_lds(
      (const __attribute__((address_space(1))) char*)g,
      (__attribute__((address_space(3))) char*)lds, 16, 0, 0);
}

// One block: 64 rows x 128 cols (full N). K=1152 over {xb, s1, s2}. 4 waves 2x2,
// each wave 32 rows x 64 cols (2x4 frags of 16x16). Fused 0.5*+relu+LayerNorm.
__global__ __launch_bounds__(256) void gemm_ln_kernel(
    const unsigned short* __restrict__ xb, const unsigned short* __restrict__ s1,
    const unsigned short* __restrict__ s2, const unsigned short* __restrict__ Bm,
    const float* __restrict__ gamma, const float* __restrict__ beta,
    float* __restrict__ out) {
  __shared__ __align__(16) unsigned short As[64 * 64];   // [row][k]
  __shared__ __align__(16) unsigned short Bs[128 * 64];  // [n][k]
  __shared__ float rsum[64][2];
  __shared__ float rsq[64][2];

  const int t = threadIdx.x;
  const int lane = t & 63;
  const int wid = t >> 6;
  const int wr = wid >> 1, wc = wid & 1;
  const int m0 = blockIdx.x * 64;

  f32x4 acc[2][4];
  #pragma unroll
  for (int i = 0; i < 2; ++i)
    #pragma unroll
    for (int j = 0; j < 4; ++j) acc[i][j] = {0.f, 0.f, 0.f, 0.f};

  for (int kt = 0; kt < 18; ++kt) {
    const unsigned short* aptr; int astride, kloc;
    if (kt < 2)       { aptr = xb; astride = 128; kloc = kt * 64; }
    else if (kt < 10) { aptr = s1; astride = 512; kloc = (kt - 2) * 64; }
    else              { aptr = s2; astride = 512; kloc = (kt - 10) * 64; }

    #pragma unroll
    for (int i = 0; i < 2; ++i) {                 // A: 512 x 16B chunks
      int chunk = i * 256 + t;
      int r = chunk >> 3, c8 = chunk & 7;
      gload16(As + chunk * 8, aptr + (size_t)(m0 + r) * astride + kloc + c8 * 8);
    }
    #pragma unroll
    for (int i = 0; i < 4; ++i) {                 // B: 1024 x 16B chunks
      int chunk = i * 256 + t;
      int r = chunk >> 3, c8 = chunk & 7;
      gload16(Bs + chunk * 8, Bm + (size_t)r * 1152 + kt * 64 + c8 * 8);
    }
    __syncthreads();

    #pragma unroll
    for (int kk = 0; kk < 2; ++kk) {
      bf16x8 a[2], b[4];
      int ko = kk * 32 + ((lane >> 4) << 3);
      #pragma unroll
      for (int mf = 0; mf < 2; ++mf) {
        int row = wr * 32 + mf * 16 + (lane & 15);
        a[mf] = *(const bf16x8*)(As + row * 64 + ko);
      }
      #pragma unroll
      for (int nf = 0; nf < 4; ++nf) {
        int n = wc * 64 + nf * 16 + (lane & 15);
        b[nf] = *(const bf16x8*)(Bs + n * 64 + ko);
      }
      #pragma unroll
      for (int mf = 0; mf < 2; ++mf)
        #pragma unroll
        for (int nf = 0; nf < 4; ++nf)
          acc[mf][nf] = __builtin_amdgcn_mfma_f32_16x16x32_bf16(a[mf], b[nf], acc[mf][nf], 0, 0, 0);
    }
    __syncthreads();
  }

  // epilogue: h = relu(0.5*acc); LayerNorm over 128 cols per row
  float g[4], bta[4];
  #pragma unroll
  for (int nf = 0; nf < 4; ++nf) {
    int n = wc * 64 + nf * 16 + (lane & 15);
    g[nf] = gamma[n]; bta[nf] = beta[n];
  }

  #pragma unroll
  for (int mf = 0; mf < 2; ++mf) {
    #pragma unroll
    for (int r = 0; r < 4; ++r) {
      float ps = 0.f, pq = 0.f;
      #pragma unroll
      for (int nf = 0; nf < 4; ++nf) {
        float v = fmaxf(0.5f * acc[mf][nf][r], 0.0f);
        acc[mf][nf][r] = v;
        ps += v; pq += v * v;
      }
      #pragma unroll
      for (int d = 1; d < 16; d <<= 1) {
        ps += __shfl_xor(ps, d);
        pq += __shfl_xor(pq, d);
      }
      if ((lane & 15) == 0) {
        int m = wr * 32 + mf * 16 + ((lane >> 4) << 2) + r;
        rsum[m][wc] = ps;
        rsq[m][wc] = pq;
      }
    }
  }
  __syncthreads();

  #pragma unroll
  for (int mf = 0; mf < 2; ++mf) {
    #pragma unroll
    for (int r = 0; r < 4; ++r) {
      int m = wr * 32 + mf * 16 + ((lane >> 4) << 2) + r;
      float sum = rsum[m][0] + rsum[m][1];
      float sq  = rsq[m][0] + rsq[m][1];
      float mu = sum * (1.0f / 128.0f);
      float var = fmaxf(sq * (1.0f / 128.0f) - mu * mu, 0.0f);
      float rstd = rsqrtf(var + 1e-5f);
      int mg = m0 + m;
      if (mg < N_NODES) {
        #pragma unroll
        for (int nf = 0; nf < 4; ++nf) {
          int n = wc * 64 + nf * 16 + (lane & 15);
          out[(size_t)mg * 128 + n] = (acc[mf][nf][r] - mu) * rstd * g[nf] + bta[nf];
        }
      }
    }
  }
}

extern "C" void kernel_launch(void* const* d_in, const int* in_sizes, int n_in,
                              void* d_out, int out_size, void* d_ws, size_t ws_size,
                              hipStream_t stream) {
  const float* x    = (const float*)d_in[0];
  const int*   ei1  = (const int*)d_in[1];
  const int*   ei2  = (const int*)d_in[2];
  const float* W1a  = (const float*)d_in[3];
  const float* W2a  = (const float*)d_in[4];
  const float* W1b  = (const float*)d_in[5];
  const float* W2b  = (const float*)d_in[6];
  const float* gamma = (const float*)d_in[7];
  const float* beta  = (const float*)d_in[8];
  float* out = (float*)d_out;

  char* w = (char*)d_ws;
  auto alloc = [&](size_t b) { char* p = w; w += (b + 255) & ~(size_t)255; return p; };
  int* cnt1 = (int*)alloc((size_t)N_NODES * 4);
  int* cnt2 = (int*)alloc((size_t)N_NODES * 4);
  int* off1 = (int*)alloc((size_t)(N_NODES + 1) * 4);
  int* off2 = (int*)alloc((size_t)(N_NODES + 1) * 4);
  int* cur1 = (int*)alloc((size_t)N_NODES * 4);
  int* cur2 = (int*)alloc((size_t)N_NODES * 4);
  int* csr1 = (int*)alloc((size_t)N_EDGES * 4);
  int* csr2 = (int*)alloc((size_t)N_EDGES * 4);
  unsigned short* xb = (unsigned short*)alloc((size_t)M_PAD * 128 * 2);
  unsigned short* s1 = (unsigned short*)alloc((size_t)M_PAD * 512 * 2);
  unsigned short* s2 = (unsigned short*)alloc((size_t)M_PAD * 512 * 2);
  unsigned short* Bm = (unsigned short*)alloc((size_t)128 * 1152 * 2);

  zero_kernel<<<196, 256, 0, stream>>>(cnt1, N_NODES);
  zero_kernel<<<196, 256, 0, stream>>>(cnt2, N_NODES);
  hist_kernel<<<2344, 256, 0, stream>>>(ei1 + N_EDGES, cnt1, N_EDGES);
  hist_kernel<<<2344, 256, 0, stream>>>(ei2 + N_EDGES, cnt2, N_EDGES);
  scan_kernel<<<2, 1024, 0, stream>>>(cnt1, cnt2, off1, off2, cur1, cur2, N_NODES);
  fill_kernel<<<2344, 256, 0, stream>>>(ei1, ei1 + N_EDGES, cur1, csr1, N_EDGES);
  fill_kernel<<<2344, 256, 0, stream>>>(ei2, ei2 + N_EDGES, cur2, csr2, N_EDGES);
  aggregate_kernel<<<12500, 256, 0, stream>>>(x, csr1, off1, s1);
  aggregate_kernel<<<12500, 256, 0, stream>>>(x, csr2, off2, s2);
  convx_kernel<<<12500, 256, 0, stream>>>(x, xb);
  buildB_kernel<<<576, 256, 0, stream>>>(W1a, W2a, W1b, W2b, Bm);
  gemm_ln_kernel<<<782, 256, 0, stream>>>(xb, s1, s2, Bm, gamma, beta, out);
}

// Round 2
// 336.337 us; speedup vs baseline: 1.2108x; 1.2108x over previous
//
#include <hip/hip_runtime.h>
#include <stdint.h>

#define N_NODES 50000
#define N_EDGES 600000
#define M_PAD   50048   // padded rows for GEMM tiles (multiple of 64)
#define NCHUNK  196     // ceil(50000/256)

typedef __bf16 bf16x8 __attribute__((ext_vector_type(8)));
typedef float  f32x4  __attribute__((ext_vector_type(4)));

__device__ __forceinline__ unsigned short f2bf(float f) {
  union { float f; unsigned u; } v; v.f = f;
  unsigned r = v.u + 0x7FFF + ((v.u >> 16) & 1);  // round-to-nearest-even
  return (unsigned short)(r >> 16);
}

__global__ void hist2_kernel(const int* __restrict__ d1, const int* __restrict__ d2,
                             int* __restrict__ c1, int* __restrict__ c2, int e) {
  const int* dst = blockIdx.y ? d2 : d1;
  int* cnt = blockIdx.y ? c2 : c1;
  int i = blockIdx.x * blockDim.x + threadIdx.x;
  if (i < e) atomicAdd(&cnt[dst[i]], 1);
}

// Pass 1: per-256-chunk exclusive scan (wave shuffle + LDS cross-wave), block sums out.
__global__ void scan_blocks_kernel(const int* __restrict__ cnt1, const int* __restrict__ cnt2,
                                   int* __restrict__ off1, int* __restrict__ off2,
                                   int* __restrict__ bsum, int n) {
  const int* cnt = blockIdx.y ? cnt2 : cnt1;
  int* off = blockIdx.y ? off2 : off1;
  int* bs = bsum + blockIdx.y * NCHUNK;
  int tid = threadIdx.x, lane = tid & 63, wid = tid >> 6;
  int i = blockIdx.x * 256 + tid;
  int v = (i < n) ? cnt[i] : 0;
  int val = v;
  #pragma unroll
  for (int d = 1; d < 64; d <<= 1) {
    int t = __shfl_up(val, d);
    if (lane >= d) val += t;
  }
  __shared__ int ws[4];
  if (lane == 63) ws[wid] = val;
  __syncthreads();
  int wbase = 0;
  #pragma unroll
  for (int w = 0; w < 3; ++w) wbase += (w < wid) ? ws[w] : 0;
  int inc = wbase + val;
  if (i < n) off[i] = inc - v;     // chunk-local exclusive
  if (tid == 255) bs[blockIdx.x] = inc;
}

// Pass 2: scan the 196 block sums (one block per relation); also writes off[n].
__global__ void scan_mid_kernel(const int* __restrict__ bsum, int* __restrict__ bbase,
                                int* __restrict__ off1, int* __restrict__ off2, int nb, int n) {
  int rel = blockIdx.x;
  const int* bs = bsum + rel * NCHUNK;
  int* bb = bbase + rel * NCHUNK;
  int tid = threadIdx.x, lane = tid & 63, wid = tid >> 6;
  int v = (tid < nb) ? bs[tid] : 0;
  int val = v;
  #pragma unroll
  for (int d = 1; d < 64; d <<= 1) {
    int t = __shfl_up(val, d);
    if (lane >= d) val += t;
  }
  __shared__ int ws[4];
  if (lane == 63) ws[wid] = val;
  __syncthreads();
  int wbase = 0;
  #pragma unroll
  for (int w = 0; w < 3; ++w) wbase += (w < wid) ? ws[w] : 0;
  int inc = wbase + val;
  if (tid < nb) bb[tid] = inc - v;
  if (tid == 255) { int* off = rel ? off2 : off1; off[n] = inc; }
}

// Pass 3: add block bases; produce final off and the cursor copy.
__global__ void scan_add_kernel(const int* __restrict__ bbase,
                                int* __restrict__ off1, int* __restrict__ off2,
                                int* __restrict__ cur1, int* __restrict__ cur2, int n) {
  int* off = blockIdx.y ? off2 : off1;
  int* cur = blockIdx.y ? cur2 : cur1;
  int b = bbase[blockIdx.y * NCHUNK + blockIdx.x];
  int i = blockIdx.x * 256 + threadIdx.x;
  if (i < n) { int o = off[i] + b; off[i] = o; cur[i] = o; }
}

__global__ void fill2_kernel(const int* __restrict__ ei1, const int* __restrict__ ei2,
                             int* __restrict__ cur1, int* __restrict__ cur2,
                             int* __restrict__ csr1, int* __restrict__ csr2, int e) {
  const int* ei = blockIdx.y ? ei2 : ei1;
  int* cur = blockIdx.y ? cur2 : cur1;
  int* csr = blockIdx.y ? csr2 : csr1;
  int i = blockIdx.x * blockDim.x + threadIdx.x;
  if (i < e) {
    int d = ei[e + i];           // dst row
    int p = atomicAdd(&cur[d], 1);
    csr[p] = ei[i];              // src row
  }
}

// One wave per node; lane owns channels {2*lane, 2*lane+1}. Sequential reduce
// over the node's CSR edge list -> mean/max/min/sum written bf16 [N][512].
// grid.y selects relation.
__global__ void aggregate_kernel(const float* __restrict__ x,
                                 const int* __restrict__ csr1, const int* __restrict__ off1,
                                 unsigned short* __restrict__ sa,
                                 const int* __restrict__ csr2, const int* __restrict__ off2,
                                 unsigned short* __restrict__ sb) {
  const int* csr = blockIdx.y ? csr2 : csr1;
  const int* off = blockIdx.y ? off2 : off1;
  unsigned short* s = blockIdx.y ? sb : sa;
  int wid = blockIdx.x * 4 + (threadIdx.x >> 6);
  int lane = threadIdx.x & 63;
  if (wid >= N_NODES) return;
  int beg = off[wid], end = off[wid + 1];
  float s0 = 0.f, s1v = 0.f;
  float mx0 = -3.0e38f, mx1 = -3.0e38f;
  float mn0 = 3.0e38f, mn1 = 3.0e38f;
  for (int e = beg; e < end; ++e) {
    int sr = csr[e];
    float2 v = *((const float2*)(x + (size_t)sr * 128) + lane);
    s0 += v.x; s1v += v.y;
    mx0 = fmaxf(mx0, v.x); mx1 = fmaxf(mx1, v.y);
    mn0 = fminf(mn0, v.x); mn1 = fminf(mn1, v.y);
  }
  int deg = end - beg;
  float inv = (deg > 0) ? (1.0f / (float)deg) : 0.0f;
  float me0 = s0 * inv, me1 = s1v * inv;
  if (deg == 0) { mx0 = mx1 = mn0 = mn1 = 0.f; }
  unsigned short* row = s + (size_t)wid * 512;
  *(ushort2*)(row +   0 + 2 * lane) = make_ushort2(f2bf(me0), f2bf(me1));
  *(ushort2*)(row + 128 + 2 * lane) = make_ushort2(f2bf(mx0), f2bf(mx1));
  *(ushort2*)(row + 256 + 2 * lane) = make_ushort2(f2bf(mn0), f2bf(mn1));
  *(ushort2*)(row + 384 + 2 * lane) = make_ushort2(f2bf(s0),  f2bf(s1v));
}

__global__ void convx_kernel(const float* __restrict__ x, unsigned short* __restrict__ xb) {
  int i = blockIdx.x * blockDim.x + threadIdx.x;  // float2 index
  if (i < N_NODES * 64) {
    float2 v = ((const float2*)x)[i];
    ((ushort2*)xb)[i] = make_ushort2(f2bf(v.x), f2bf(v.y));
  }
}

// B matrix [n=128][k=1152] bf16: k<128 -> W1_r1+W1_r2 ; 128..640 -> W2_r1 ; rest W2_r2
__global__ void buildB_kernel(const float* __restrict__ W1a, const float* __restrict__ W2a,
                              const float* __restrict__ W1b, const float* __restrict__ W2b,
                              unsigned short* __restrict__ Bm) {
  int i = blockIdx.x * blockDim.x + threadIdx.x;
  if (i >= 128 * 1152) return;
  int n = i / 1152, k = i % 1152;
  float v;
  if (k < 128)      v = W1a[n * 128 + k] + W1b[n * 128 + k];
  else if (k < 640) v = W2a[n * 512 + (k - 128)];
  else              v = W2b[n * 512 + (k - 640)];
  Bm[i] = f2bf(v);
}

__device__ __forceinline__ void gload16(void* lds, const void* g) {
  __builtin_amdgcn_global_load_lds(
      (const __attribute__((address_space(1))) char*)g,
      (__attribute__((address_space(3))) char*)lds, 16, 0, 0);
}

// One block: 64 rows x 128 cols (full N). K=1152 over {xb, s1, s2}. 4 waves 2x2,
// each wave 32 rows x 64 cols (2x4 frags of 16x16). Fused 0.5*+relu+LayerNorm.
__global__ __launch_bounds__(256) void gemm_ln_kernel(
    const unsigned short* __restrict__ xb, const unsigned short* __restrict__ s1,
    const unsigned short* __restrict__ s2, const unsigned short* __restrict__ Bm,
    const float* __restrict__ gamma, const float* __restrict__ beta,
    float* __restrict__ out) {
  __shared__ __align__(16) unsigned short As[64 * 64];   // [row][k]
  __shared__ __align__(16) unsigned short Bs[128 * 64];  // [n][k]
  __shared__ float rsum[64][2];
  __shared__ float rsq[64][2];

  const int t = threadIdx.x;
  const int lane = t & 63;
  const int wid = t >> 6;
  const int wr = wid >> 1, wc = wid & 1;
  const int m0 = blockIdx.x * 64;

  f32x4 acc[2][4];
  #pragma unroll
  for (int i = 0; i < 2; ++i)
    #pragma unroll
    for (int j = 0; j < 4; ++j) acc[i][j] = {0.f, 0.f, 0.f, 0.f};

  for (int kt = 0; kt < 18; ++kt) {
    const unsigned short* aptr; int astride, kloc;
    if (kt < 2)       { aptr = xb; astride = 128; kloc = kt * 64; }
    else if (kt < 10) { aptr = s1; astride = 512; kloc = (kt - 2) * 64; }
    else              { aptr = s2; astride = 512; kloc = (kt - 10) * 64; }

    #pragma unroll
    for (int i = 0; i < 2; ++i) {                 // A: 512 x 16B chunks
      int chunk = i * 256 + t;
      int r = chunk >> 3, c8 = chunk & 7;
      gload16(As + chunk * 8, aptr + (size_t)(m0 + r) * astride + kloc + c8 * 8);
    }
    #pragma unroll
    for (int i = 0; i < 4; ++i) {                 // B: 1024 x 16B chunks
      int chunk = i * 256 + t;
      int r = chunk >> 3, c8 = chunk & 7;
      gload16(Bs + chunk * 8, Bm + (size_t)r * 1152 + kt * 64 + c8 * 8);
    }
    __syncthreads();

    #pragma unroll
    for (int kk = 0; kk < 2; ++kk) {
      bf16x8 a[2], b[4];
      int ko = kk * 32 + ((lane >> 4) << 3);
      #pragma unroll
      for (int mf = 0; mf < 2; ++mf) {
        int row = wr * 32 + mf * 16 + (lane & 15);
        a[mf] = *(const bf16x8*)(As + row * 64 + ko);
      }
      #pragma unroll
      for (int nf = 0; nf < 4; ++nf) {
        int n = wc * 64 + nf * 16 + (lane & 15);
        b[nf] = *(const bf16x8*)(Bs + n * 64 + ko);
      }
      #pragma unroll
      for (int mf = 0; mf < 2; ++mf)
        #pragma unroll
        for (int nf = 0; nf < 4; ++nf)
          acc[mf][nf] = __builtin_amdgcn_mfma_f32_16x16x32_bf16(a[mf], b[nf], acc[mf][nf], 0, 0, 0);
    }
    __syncthreads();
  }

  // epilogue: h = relu(0.5*acc); LayerNorm over 128 cols per row
  float g[4], bta[4];
  #pragma unroll
  for (int nf = 0; nf < 4; ++nf) {
    int n = wc * 64 + nf * 16 + (lane & 15);
    g[nf] = gamma[n]; bta[nf] = beta[n];
  }

  #pragma unroll
  for (int mf = 0; mf < 2; ++mf) {
    #pragma unroll
    for (int r = 0; r < 4; ++r) {
      float ps = 0.f, pq = 0.f;
      #pragma unroll
      for (int nf = 0; nf < 4; ++nf) {
        float v = fmaxf(0.5f * acc[mf][nf][r], 0.0f);
        acc[mf][nf][r] = v;
        ps += v; pq += v * v;
      }
      #pragma unroll
      for (int d = 1; d < 16; d <<= 1) {
        ps += __shfl_xor(ps, d);
        pq += __shfl_xor(pq, d);
      }
      if ((lane & 15) == 0) {
        int m = wr * 32 + mf * 16 + ((lane >> 4) << 2) + r;
        rsum[m][wc] = ps;
        rsq[m][wc] = pq;
      }
    }
  }
  __syncthreads();

  #pragma unroll
  for (int mf = 0; mf < 2; ++mf) {
    #pragma unroll
    for (int r = 0; r < 4; ++r) {
      int m = wr * 32 + mf * 16 + ((lane >> 4) << 2) + r;
      float sum = rsum[m][0] + rsum[m][1];
      float sq  = rsq[m][0] + rsq[m][1];
      float mu = sum * (1.0f / 128.0f);
      float var = fmaxf(sq * (1.0f / 128.0f) - mu * mu, 0.0f);
      float rstd = rsqrtf(var + 1e-5f);
      int mg = m0 + m;
      if (mg < N_NODES) {
        #pragma unroll
        for (int nf = 0; nf < 4; ++nf) {
          int n = wc * 64 + nf * 16 + (lane & 15);
          out[(size_t)mg * 128 + n] = (acc[mf][nf][r] - mu) * rstd * g[nf] + bta[nf];
        }
      }
    }
  }
}

extern "C" void kernel_launch(void* const* d_in, const int* in_sizes, int n_in,
                              void* d_out, int out_size, void* d_ws, size_t ws_size,
                              hipStream_t stream) {
  const float* x    = (const float*)d_in[0];
  const int*   ei1  = (const int*)d_in[1];
  const int*   ei2  = (const int*)d_in[2];
  const float* W1a  = (const float*)d_in[3];
  const float* W2a  = (const float*)d_in[4];
  const float* W1b  = (const float*)d_in[5];
  const float* W2b  = (const float*)d_in[6];
  const float* gamma = (const float*)d_in[7];
  const float* beta  = (const float*)d_in[8];
  float* out = (float*)d_out;

  char* w = (char*)d_ws;
  auto alloc = [&](size_t b) { char* p = w; w += (b + 255) & ~(size_t)255; return p; };
  int* cnt1 = (int*)alloc((size_t)N_NODES * 4);
  int* cnt2 = (int*)alloc((size_t)N_NODES * 4);
  int* off1 = (int*)alloc((size_t)(N_NODES + 1) * 4);
  int* off2 = (int*)alloc((size_t)(N_NODES + 1) * 4);
  int* cur1 = (int*)alloc((size_t)N_NODES * 4);
  int* cur2 = (int*)alloc((size_t)N_NODES * 4);
  int* csr1 = (int*)alloc((size_t)N_EDGES * 4);
  int* csr2 = (int*)alloc((size_t)N_EDGES * 4);
  int* bsum = (int*)alloc((size_t)2 * NCHUNK * 4);
  int* bbase = (int*)alloc((size_t)2 * NCHUNK * 4);
  unsigned short* xb = (unsigned short*)alloc((size_t)M_PAD * 128 * 2);
  unsigned short* s1 = (unsigned short*)alloc((size_t)M_PAD * 512 * 2);
  unsigned short* s2 = (unsigned short*)alloc((size_t)M_PAD * 512 * 2);
  unsigned short* Bm = (unsigned short*)alloc((size_t)128 * 1152 * 2);

  hipMemsetAsync(cnt1, 0, (size_t)N_NODES * 4, stream);
  hipMemsetAsync(cnt2, 0, (size_t)N_NODES * 4, stream);
  hist2_kernel<<<dim3(2344, 2), 256, 0, stream>>>(ei1 + N_EDGES, ei2 + N_EDGES, cnt1, cnt2, N_EDGES);
  scan_blocks_kernel<<<dim3(NCHUNK, 2), 256, 0, stream>>>(cnt1, cnt2, off1, off2, bsum, N_NODES);
  scan_mid_kernel<<<2, 256, 0, stream>>>(bsum, bbase, off1, off2, NCHUNK, N_NODES);
  scan_add_kernel<<<dim3(NCHUNK, 2), 256, 0, stream>>>(bbase, off1, off2, cur1, cur2, N_NODES);
  fill2_kernel<<<dim3(2344, 2), 256, 0, stream>>>(ei1, ei2, cur1, cur2, csr1, csr2, N_EDGES);
  convx_kernel<<<12500, 256, 0, stream>>>(x, xb);
  aggregate_kernel<<<dim3(12500, 2), 256, 0, stream>>>(x, csr1, off1, s1, csr2, off2, s2);
  buildB_kernel<<<576, 256, 0, stream>>>(W1a, W2a, W1b, W2b, Bm);
  gemm_ln_kernel<<<782, 256, 0, stream>>>(xb, s1, s2, Bm, gamma, beta, out);
}

// Round 3
// 269.769 us; speedup vs baseline: 1.5096x; 1.2468x over previous
//
#include <hip/hip_runtime.h>
#include <stdint.h>

#define N_NODES 50000
#define N_EDGES 600000
#define M_PAD   50048   // padded rows for GEMM tiles (multiple of 64)
#define NCHUNK  196     // ceil(50000/256)

typedef __bf16 bf16x8 __attribute__((ext_vector_type(8)));
typedef float  f32x4  __attribute__((ext_vector_type(4)));

__device__ __forceinline__ unsigned short f2bf(float f) {
  union { float f; unsigned u; } v; v.f = f;
  unsigned r = v.u + 0x7FFF + ((v.u >> 16) & 1);  // round-to-nearest-even
  return (unsigned short)(r >> 16);
}

__device__ __forceinline__ float bf2f(unsigned short u) {
  union { unsigned u; float f; } v; v.u = (unsigned)u << 16; return v.f;
}

__global__ void hist2_kernel(const int* __restrict__ d1, const int* __restrict__ d2,
                             int* __restrict__ c1, int* __restrict__ c2, int e) {
  const int* dst = blockIdx.y ? d2 : d1;
  int* cnt = blockIdx.y ? c2 : c1;
  int i = blockIdx.x * blockDim.x + threadIdx.x;
  if (i < e) atomicAdd(&cnt[dst[i]], 1);
}

// Pass 1: per-256-chunk exclusive scan (wave shuffle + LDS cross-wave), block sums out.
__global__ void scan_blocks_kernel(const int* __restrict__ cnt1, const int* __restrict__ cnt2,
                                   int* __restrict__ off1, int* __restrict__ off2,
                                   int* __restrict__ bsum, int n) {
  const int* cnt = blockIdx.y ? cnt2 : cnt1;
  int* off = blockIdx.y ? off2 : off1;
  int* bs = bsum + blockIdx.y * NCHUNK;
  int tid = threadIdx.x, lane = tid & 63, wid = tid >> 6;
  int i = blockIdx.x * 256 + tid;
  int v = (i < n) ? cnt[i] : 0;
  int val = v;
  #pragma unroll
  for (int d = 1; d < 64; d <<= 1) {
    int t = __shfl_up(val, d);
    if (lane >= d) val += t;
  }
  __shared__ int ws[4];
  if (lane == 63) ws[wid] = val;
  __syncthreads();
  int wbase = 0;
  #pragma unroll
  for (int w = 0; w < 3; ++w) wbase += (w < wid) ? ws[w] : 0;
  int inc = wbase + val;
  if (i < n) off[i] = inc - v;     // chunk-local exclusive
  if (tid == 255) bs[blockIdx.x] = inc;
}

// Pass 2: scan the 196 block sums (one block per relation); also writes off[n].
__global__ void scan_mid_kernel(const int* __restrict__ bsum, int* __restrict__ bbase,
                                int* __restrict__ off1, int* __restrict__ off2, int nb, int n) {
  int rel = blockIdx.x;
  const int* bs = bsum + rel * NCHUNK;
  int* bb = bbase + rel * NCHUNK;
  int tid = threadIdx.x, lane = tid & 63, wid = tid >> 6;
  int v = (tid < nb) ? bs[tid] : 0;
  int val = v;
  #pragma unroll
  for (int d = 1; d < 64; d <<= 1) {
    int t = __shfl_up(val, d);
    if (lane >= d) val += t;
  }
  __shared__ int ws[4];
  if (lane == 63) ws[wid] = val;
  __syncthreads();
  int wbase = 0;
  #pragma unroll
  for (int w = 0; w < 3; ++w) wbase += (w < wid) ? ws[w] : 0;
  int inc = wbase + val;
  if (tid < nb) bb[tid] = inc - v;
  if (tid == 255) { int* off = rel ? off2 : off1; off[n] = inc; }
}

// Pass 3: add block bases; produce final off and the cursor copy.
__global__ void scan_add_kernel(const int* __restrict__ bbase,
                                int* __restrict__ off1, int* __restrict__ off2,
                                int* __restrict__ cur1, int* __restrict__ cur2, int n) {
  int* off = blockIdx.y ? off2 : off1;
  int* cur = blockIdx.y ? cur2 : cur1;
  int b = bbase[blockIdx.y * NCHUNK + blockIdx.x];
  int i = blockIdx.x * 256 + threadIdx.x;
  if (i < n) { int o = off[i] + b; off[i] = o; cur[i] = o; }
}

__global__ void fill2_kernel(const int* __restrict__ ei1, const int* __restrict__ ei2,
                             int* __restrict__ cur1, int* __restrict__ cur2,
                             int* __restrict__ csr1, int* __restrict__ csr2, int e) {
  const int* ei = blockIdx.y ? ei2 : ei1;
  int* cur = blockIdx.y ? cur2 : cur1;
  int* csr = blockIdx.y ? csr2 : csr1;
  int i = blockIdx.x * blockDim.x + threadIdx.x;
  if (i < e) {
    int d = ei[e + i];           // dst row
    int p = atomicAdd(&cur[d], 1);
    csr[p] = ei[i];              // src row
  }
}

__global__ void convx_kernel(const float* __restrict__ x, unsigned short* __restrict__ xb) {
  int i = blockIdx.x * blockDim.x + threadIdx.x;  // float2 index
  if (i < N_NODES * 64) {
    float2 v = ((const float2*)x)[i];
    ((ushort2*)xb)[i] = make_ushort2(f2bf(v.x), f2bf(v.y));
  }
}

// One wave per node. Half-wave per edge: lanes 0-31 handle even edges, 32-63 odd;
// each lane owns 4 channels (ushort4 = 8B gather from bf16 x). csr-index prefetch
// breaks the index->gather dependency. Cross-half combine via shfl_xor(32).
// Output bf16 [N][512] = mean|max|min|sum. grid.y selects relation.
__global__ void aggregate_kernel(const unsigned short* __restrict__ xb,
                                 const int* __restrict__ csr1, const int* __restrict__ off1,
                                 unsigned short* __restrict__ sa,
                                 const int* __restrict__ csr2, const int* __restrict__ off2,
                                 unsigned short* __restrict__ sb) {
  const int* csr = blockIdx.y ? csr2 : csr1;
  const int* off = blockIdx.y ? off2 : off1;
  unsigned short* s = blockIdx.y ? sb : sa;
  int wid = blockIdx.x * 4 + (threadIdx.x >> 6);
  int lane = threadIdx.x & 63;
  if (wid >= N_NODES) return;
  int beg = off[wid], end = off[wid + 1];
  int half = lane >> 5, l5 = lane & 31;

  float sm0 = 0.f, sm1 = 0.f, sm2 = 0.f, sm3 = 0.f;
  float mx0 = -3.0e38f, mx1 = -3.0e38f, mx2 = -3.0e38f, mx3 = -3.0e38f;
  float mn0 = 3.0e38f, mn1 = 3.0e38f, mn2 = 3.0e38f, mn3 = 3.0e38f;

  int e = beg + half;
  int sr_next = (e < end) ? csr[e] : 0;
  while (e < end) {
    int sr = sr_next;
    int en = e + 2;
    if (en < end) sr_next = csr[en];
    ushort4 v = *(const ushort4*)(xb + (size_t)sr * 128 + 4 * l5);
    float f0 = bf2f(v.x), f1 = bf2f(v.y), f2v = bf2f(v.z), f3 = bf2f(v.w);
    sm0 += f0; sm1 += f1; sm2 += f2v; sm3 += f3;
    mx0 = fmaxf(mx0, f0); mx1 = fmaxf(mx1, f1); mx2 = fmaxf(mx2, f2v); mx3 = fmaxf(mx3, f3);
    mn0 = fminf(mn0, f0); mn1 = fminf(mn1, f1); mn2 = fminf(mn2, f2v); mn3 = fminf(mn3, f3);
    e = en;
  }
  // combine the two half-wave partials (lane i <-> lane i+32, same channels)
  sm0 += __shfl_xor(sm0, 32); sm1 += __shfl_xor(sm1, 32);
  sm2 += __shfl_xor(sm2, 32); sm3 += __shfl_xor(sm3, 32);
  mx0 = fmaxf(mx0, __shfl_xor(mx0, 32)); mx1 = fmaxf(mx1, __shfl_xor(mx1, 32));
  mx2 = fmaxf(mx2, __shfl_xor(mx2, 32)); mx3 = fmaxf(mx3, __shfl_xor(mx3, 32));
  mn0 = fminf(mn0, __shfl_xor(mn0, 32)); mn1 = fminf(mn1, __shfl_xor(mn1, 32));
  mn2 = fminf(mn2, __shfl_xor(mn2, 32)); mn3 = fminf(mn3, __shfl_xor(mn3, 32));

  int deg = end - beg;
  float inv = (deg > 0) ? (1.0f / (float)deg) : 0.0f;
  if (deg == 0) {
    mx0 = mx1 = mx2 = mx3 = 0.f;
    mn0 = mn1 = mn2 = mn3 = 0.f;
  }
  unsigned short* row = s + (size_t)wid * 512;
  if (half == 0) {
    ushort4 m4; m4.x = f2bf(sm0 * inv); m4.y = f2bf(sm1 * inv); m4.z = f2bf(sm2 * inv); m4.w = f2bf(sm3 * inv);
    *(ushort4*)(row + 4 * l5) = m4;
    ushort4 x4; x4.x = f2bf(mx0); x4.y = f2bf(mx1); x4.z = f2bf(mx2); x4.w = f2bf(mx3);
    *(ushort4*)(row + 128 + 4 * l5) = x4;
  } else {
    ushort4 n4; n4.x = f2bf(mn0); n4.y = f2bf(mn1); n4.z = f2bf(mn2); n4.w = f2bf(mn3);
    *(ushort4*)(row + 256 + 4 * l5) = n4;
    ushort4 s4; s4.x = f2bf(sm0); s4.y = f2bf(sm1); s4.z = f2bf(sm2); s4.w = f2bf(sm3);
    *(ushort4*)(row + 384 + 4 * l5) = s4;
  }
}

// B matrix [n=128][k=1152] bf16: k<128 -> W1_r1+W1_r2 ; 128..640 -> W2_r1 ; rest W2_r2
__global__ void buildB_kernel(const float* __restrict__ W1a, const float* __restrict__ W2a,
                              const float* __restrict__ W1b, const float* __restrict__ W2b,
                              unsigned short* __restrict__ Bm) {
  int i = blockIdx.x * blockDim.x + threadIdx.x;
  if (i >= 128 * 1152) return;
  int n = i / 1152, k = i % 1152;
  float v;
  if (k < 128)      v = W1a[n * 128 + k] + W1b[n * 128 + k];
  else if (k < 640) v = W2a[n * 512 + (k - 128)];
  else              v = W2b[n * 512 + (k - 640)];
  Bm[i] = f2bf(v);
}

__device__ __forceinline__ void gload16(void* lds, const void* g) {
  __builtin_amdgcn_global_load_lds(
      (const __attribute__((address_space(1))) char*)g,
      (__attribute__((address_space(3))) char*)lds, 16, 0, 0);
}

// One block: 64 rows x 128 cols (full N). K=1152 over {xb, s1, s2}. 4 waves 2x2,
// each wave 32 rows x 64 cols (2x4 frags of 16x16). Fused 0.5*+relu+LayerNorm.
__global__ __launch_bounds__(256) void gemm_ln_kernel(
    const unsigned short* __restrict__ xb, const unsigned short* __restrict__ s1,
    const unsigned short* __restrict__ s2, const unsigned short* __restrict__ Bm,
    const float* __restrict__ gamma, const float* __restrict__ beta,
    float* __restrict__ out) {
  __shared__ __align__(16) unsigned short As[64 * 64];   // [row][k]
  __shared__ __align__(16) unsigned short Bs[128 * 64];  // [n][k]
  __shared__ float rsum[64][2];
  __shared__ float rsq[64][2];

  const int t = threadIdx.x;
  const int lane = t & 63;
  const int wid = t >> 6;
  const int wr = wid >> 1, wc = wid & 1;
  const int m0 = blockIdx.x * 64;

  f32x4 acc[2][4];
  #pragma unroll
  for (int i = 0; i < 2; ++i)
    #pragma unroll
    for (int j = 0; j < 4; ++j) acc[i][j] = {0.f, 0.f, 0.f, 0.f};

  for (int kt = 0; kt < 18; ++kt) {
    const unsigned short* aptr; int astride, kloc;
    if (kt < 2)       { aptr = xb; astride = 128; kloc = kt * 64; }
    else if (kt < 10) { aptr = s1; astride = 512; kloc = (kt - 2) * 64; }
    else              { aptr = s2; astride = 512; kloc = (kt - 10) * 64; }

    #pragma unroll
    for (int i = 0; i < 2; ++i) {                 // A: 512 x 16B chunks
      int chunk = i * 256 + t;
      int r = chunk >> 3, c8 = chunk & 7;
      gload16(As + chunk * 8, aptr + (size_t)(m0 + r) * astride + kloc + c8 * 8);
    }
    #pragma unroll
    for (int i = 0; i < 4; ++i) {                 // B: 1024 x 16B chunks
      int chunk = i * 256 + t;
      int r = chunk >> 3, c8 = chunk & 7;
      gload16(Bs + chunk * 8, Bm + (size_t)r * 1152 + kt * 64 + c8 * 8);
    }
    __syncthreads();

    #pragma unroll
    for (int kk = 0; kk < 2; ++kk) {
      bf16x8 a[2], b[4];
      int ko = kk * 32 + ((lane >> 4) << 3);
      #pragma unroll
      for (int mf = 0; mf < 2; ++mf) {
        int row = wr * 32 + mf * 16 + (lane & 15);
        a[mf] = *(const bf16x8*)(As + row * 64 + ko);
      }
      #pragma unroll
      for (int nf = 0; nf < 4; ++nf) {
        int n = wc * 64 + nf * 16 + (lane & 15);
        b[nf] = *(const bf16x8*)(Bs + n * 64 + ko);
      }
      #pragma unroll
      for (int mf = 0; mf < 2; ++mf)
        #pragma unroll
        for (int nf = 0; nf < 4; ++nf)
          acc[mf][nf] = __builtin_amdgcn_mfma_f32_16x16x32_bf16(a[mf], b[nf], acc[mf][nf], 0, 0, 0);
    }
    __syncthreads();
  }

  // epilogue: h = relu(0.5*acc); LayerNorm over 128 cols per row
  float g[4], bta[4];
  #pragma unroll
  for (int nf = 0; nf < 4; ++nf) {
    int n = wc * 64 + nf * 16 + (lane & 15);
    g[nf] = gamma[n]; bta[nf] = beta[n];
  }

  #pragma unroll
  for (int mf = 0; mf < 2; ++mf) {
    #pragma unroll
    for (int r = 0; r < 4; ++r) {
      float ps = 0.f, pq = 0.f;
      #pragma unroll
      for (int nf = 0; nf < 4; ++nf) {
        float v = fmaxf(0.5f * acc[mf][nf][r], 0.0f);
        acc[mf][nf][r] = v;
        ps += v; pq += v * v;
      }
      #pragma unroll
      for (int d = 1; d < 16; d <<= 1) {
        ps += __shfl_xor(ps, d);
        pq += __shfl_xor(pq, d);
      }
      if ((lane & 15) == 0) {
        int m = wr * 32 + mf * 16 + ((lane >> 4) << 2) + r;
        rsum[m][wc] = ps;
        rsq[m][wc] = pq;
      }
    }
  }
  __syncthreads();

  #pragma unroll
  for (int mf = 0; mf < 2; ++mf) {
    #pragma unroll
    for (int r = 0; r < 4; ++r) {
      int m = wr * 32 + mf * 16 + ((lane >> 4) << 2) + r;
      float sum = rsum[m][0] + rsum[m][1];
      float sq  = rsq[m][0] + rsq[m][1];
      float mu = sum * (1.0f / 128.0f);
      float var = fmaxf(sq * (1.0f / 128.0f) - mu * mu, 0.0f);
      float rstd = rsqrtf(var + 1e-5f);
      int mg = m0 + m;
      if (mg < N_NODES) {
        #pragma unroll
        for (int nf = 0; nf < 4; ++nf) {
          int n = wc * 64 + nf * 16 + (lane & 15);
          out[(size_t)mg * 128 + n] = (acc[mf][nf][r] - mu) * rstd * g[nf] + bta[nf];
        }
      }
    }
  }
}

extern "C" void kernel_launch(void* const* d_in, const int* in_sizes, int n_in,
                              void* d_out, int out_size, void* d_ws, size_t ws_size,
                              hipStream_t stream) {
  const float* x    = (const float*)d_in[0];
  const int*   ei1  = (const int*)d_in[1];
  const int*   ei2  = (const int*)d_in[2];
  const float* W1a  = (const float*)d_in[3];
  const float* W2a  = (const float*)d_in[4];
  const float* W1b  = (const float*)d_in[5];
  const float* W2b  = (const float*)d_in[6];
  const float* gamma = (const float*)d_in[7];
  const float* beta  = (const float*)d_in[8];
  float* out = (float*)d_out;

  char* w = (char*)d_ws;
  auto alloc = [&](size_t b) { char* p = w; w += (b + 255) & ~(size_t)255; return p; };
  int* cnt1 = (int*)alloc((size_t)N_NODES * 4);
  int* cnt2 = (int*)alloc((size_t)N_NODES * 4);
  int* off1 = (int*)alloc((size_t)(N_NODES + 1) * 4);
  int* off2 = (int*)alloc((size_t)(N_NODES + 1) * 4);
  int* cur1 = (int*)alloc((size_t)N_NODES * 4);
  int* cur2 = (int*)alloc((size_t)N_NODES * 4);
  int* csr1 = (int*)alloc((size_t)N_EDGES * 4);
  int* csr2 = (int*)alloc((size_t)N_EDGES * 4);
  int* bsum = (int*)alloc((size_t)2 * NCHUNK * 4);
  int* bbase = (int*)alloc((size_t)2 * NCHUNK * 4);
  unsigned short* xb = (unsigned short*)alloc((size_t)M_PAD * 128 * 2);
  unsigned short* s1 = (unsigned short*)alloc((size_t)M_PAD * 512 * 2);
  unsigned short* s2 = (unsigned short*)alloc((size_t)M_PAD * 512 * 2);
  unsigned short* Bm = (unsigned short*)alloc((size_t)128 * 1152 * 2);

  hipMemsetAsync(cnt1, 0, (size_t)N_NODES * 4, stream);
  hipMemsetAsync(cnt2, 0, (size_t)N_NODES * 4, stream);
  hist2_kernel<<<dim3(2344, 2), 256, 0, stream>>>(ei1 + N_EDGES, ei2 + N_EDGES, cnt1, cnt2, N_EDGES);
  scan_blocks_kernel<<<dim3(NCHUNK, 2), 256, 0, stream>>>(cnt1, cnt2, off1, off2, bsum, N_NODES);
  scan_mid_kernel<<<2, 256, 0, stream>>>(bsum, bbase, off1, off2, NCHUNK, N_NODES);
  scan_add_kernel<<<dim3(NCHUNK, 2), 256, 0, stream>>>(bbase, off1, off2, cur1, cur2, N_NODES);
  fill2_kernel<<<dim3(2344, 2), 256, 0, stream>>>(ei1, ei2, cur1, cur2, csr1, csr2, N_EDGES);
  convx_kernel<<<12500, 256, 0, stream>>>(x, xb);
  aggregate_kernel<<<dim3(12500, 2), 256, 0, stream>>>(xb, csr1, off1, s1, csr2, off2, s2);
  buildB_kernel<<<576, 256, 0, stream>>>(W1a, W2a, W1b, W2b, Bm);
  gemm_ln_kernel<<<782, 256, 0, stream>>>(xb, s1, s2, Bm, gamma, beta, out);
}

// Round 4
// 258.339 us; speedup vs baseline: 1.5764x; 1.0442x over previous
//
#include <hip/hip_runtime.h>
#include <stdint.h>

#define N_NODES 50000
#define N_EDGES 600000
#define M_PAD   50048   // padded rows for GEMM tiles (multiple of 64)
#define NCHUNK  196     // ceil(50000/256)
#define NPASS   8
#define PASS_SZ 6250    // N_NODES / NPASS

typedef __bf16 bf16x8 __attribute__((ext_vector_type(8)));
typedef float  f32x4  __attribute__((ext_vector_type(4)));

__device__ __forceinline__ unsigned short f2bf(float f) {
  union { float f; unsigned u; } v; v.f = f;
  unsigned r = v.u + 0x7FFF + ((v.u >> 16) & 1);  // round-to-nearest-even
  return (unsigned short)(r >> 16);
}

__device__ __forceinline__ float bf2f(unsigned short u) {
  union { unsigned u; float f; } v; v.u = (unsigned)u << 16; return v.f;
}

__global__ void hist2_kernel(const int* __restrict__ d1, const int* __restrict__ d2,
                             int* __restrict__ c1, int* __restrict__ c2, int e) {
  const int* dst = blockIdx.y ? d2 : d1;
  int* cnt = blockIdx.y ? c2 : c1;
  int i = blockIdx.x * blockDim.x + threadIdx.x;
  if (i < e) atomicAdd(&cnt[dst[i]], 1);
}

// Pass 1: per-256-chunk exclusive scan (wave shuffle + LDS cross-wave), block sums out.
__global__ void scan_blocks_kernel(const int* __restrict__ cnt1, const int* __restrict__ cnt2,
                                   int* __restrict__ off1, int* __restrict__ off2,
                                   int* __restrict__ bsum, int n) {
  const int* cnt = blockIdx.y ? cnt2 : cnt1;
  int* off = blockIdx.y ? off2 : off1;
  int* bs = bsum + blockIdx.y * NCHUNK;
  int tid = threadIdx.x, lane = tid & 63, wid = tid >> 6;
  int i = blockIdx.x * 256 + tid;
  int v = (i < n) ? cnt[i] : 0;
  int val = v;
  #pragma unroll
  for (int d = 1; d < 64; d <<= 1) {
    int t = __shfl_up(val, d);
    if (lane >= d) val += t;
  }
  __shared__ int ws[4];
  if (lane == 63) ws[wid] = val;
  __syncthreads();
  int wbase = 0;
  #pragma unroll
  for (int w = 0; w < 3; ++w) wbase += (w < wid) ? ws[w] : 0;
  int inc = wbase + val;
  if (i < n) off[i] = inc - v;     // chunk-local exclusive
  if (tid == 255) bs[blockIdx.x] = inc;
}

// Pass 2: scan the 196 block sums (one block per relation); also writes off[n].
__global__ void scan_mid_kernel(const int* __restrict__ bsum, int* __restrict__ bbase,
                                int* __restrict__ off1, int* __restrict__ off2, int nb, int n) {
  int rel = blockIdx.x;
  const int* bs = bsum + rel * NCHUNK;
  int* bb = bbase + rel * NCHUNK;
  int tid = threadIdx.x, lane = tid & 63, wid = tid >> 6;
  int v = (tid < nb) ? bs[tid] : 0;
  int val = v;
  #pragma unroll
  for (int d = 1; d < 64; d <<= 1) {
    int t = __shfl_up(val, d);
    if (lane >= d) val += t;
  }
  __shared__ int ws[4];
  if (lane == 63) ws[wid] = val;
  __syncthreads();
  int wbase = 0;
  #pragma unroll
  for (int w = 0; w < 3; ++w) wbase += (w < wid) ? ws[w] : 0;
  int inc = wbase + val;
  if (tid < nb) bb[tid] = inc - v;
  if (tid == 255) { int* off = rel ? off2 : off1; off[n] = inc; }
}

// Pass 3: add block bases; produce final off and the cursor copy.
__global__ void scan_add_kernel(const int* __restrict__ bbase,
                                int* __restrict__ off1, int* __restrict__ off2,
                                int* __restrict__ cur1, int* __restrict__ cur2, int n) {
  int* off = blockIdx.y ? off2 : off1;
  int* cur = blockIdx.y ? cur2 : cur1;
  int b = bbase[blockIdx.y * NCHUNK + blockIdx.x];
  int i = blockIdx.x * 256 + threadIdx.x;
  if (i < n) { int o = off[i] + b; off[i] = o; cur[i] = o; }
}

// CSR scatter, dst-range partitioned into NPASS passes so that at any moment
// the whole GPU's atomics+stores target a ~650KB L2-resident region (kills the
// 75MB write-allocate thrash of the naive one-shot scatter).
__global__ void fill2_kernel(const int* __restrict__ ei1, const int* __restrict__ ei2,
                             int* __restrict__ cur1, int* __restrict__ cur2,
                             int* __restrict__ csr1, int* __restrict__ csr2, int e) {
  const int* ei = blockIdx.y ? ei2 : ei1;
  int* cur = blockIdx.y ? cur2 : cur1;
  int* csr = blockIdx.y ? csr2 : csr1;
  int i = blockIdx.x * blockDim.x + threadIdx.x;
  bool valid = (i < e);
  int d = 0, sr = 0, p = 0;
  if (valid) {
    d = ei[e + i];               // dst row
    sr = ei[i];                  // src row
    p = d / PASS_SZ;
  }
  #pragma unroll 1
  for (int pass = 0; pass < NPASS; ++pass) {
    if (valid && p == pass) {
      int pos = atomicAdd(&cur[d], 1);
      csr[pos] = sr;
    }
    __syncthreads();             // uniform: no early returns above
  }
}

__global__ void convx_kernel(const float* __restrict__ x, unsigned short* __restrict__ xb) {
  int i = blockIdx.x * blockDim.x + threadIdx.x;  // float2 index
  if (i < N_NODES * 64) {
    float2 v = ((const float2*)x)[i];
    ((ushort2*)xb)[i] = make_ushort2(f2bf(v.x), f2bf(v.y));
  }
}

// One wave per node. Half-wave per edge: lanes 0-31 handle even edges, 32-63 odd;
// each lane owns 4 channels (ushort4 = 8B gather from bf16 x). csr-index prefetch
// breaks the index->gather dependency. Cross-half combine via shfl_xor(32).
// Output bf16 [N][512] = mean|max|min|sum. grid.y selects relation.
__global__ void aggregate_kernel(const unsigned short* __restrict__ xb,
                                 const int* __restrict__ csr1, const int* __restrict__ off1,
                                 unsigned short* __restrict__ sa,
                                 const int* __restrict__ csr2, const int* __restrict__ off2,
                                 unsigned short* __restrict__ sb) {
  const int* csr = blockIdx.y ? csr2 : csr1;
  const int* off = blockIdx.y ? off2 : off1;
  unsigned short* s = blockIdx.y ? sb : sa;
  int wid = blockIdx.x * 4 + (threadIdx.x >> 6);
  int lane = threadIdx.x & 63;
  if (wid >= N_NODES) return;
  int beg = off[wid], end = off[wid + 1];
  int half = lane >> 5, l5 = lane & 31;

  float sm0 = 0.f, sm1 = 0.f, sm2 = 0.f, sm3 = 0.f;
  float mx0 = -3.0e38f, mx1 = -3.0e38f, mx2 = -3.0e38f, mx3 = -3.0e38f;
  float mn0 = 3.0e38f, mn1 = 3.0e38f, mn2 = 3.0e38f, mn3 = 3.0e38f;

  int e = beg + half;
  int sr_next = (e < end) ? csr[e] : 0;
  while (e < end) {
    int sr = sr_next;
    int en = e + 2;
    if (en < end) sr_next = csr[en];
    ushort4 v = *(const ushort4*)(xb + (size_t)sr * 128 + 4 * l5);
    float f0 = bf2f(v.x), f1 = bf2f(v.y), f2v = bf2f(v.z), f3 = bf2f(v.w);
    sm0 += f0; sm1 += f1; sm2 += f2v; sm3 += f3;
    mx0 = fmaxf(mx0, f0); mx1 = fmaxf(mx1, f1); mx2 = fmaxf(mx2, f2v); mx3 = fmaxf(mx3, f3);
    mn0 = fminf(mn0, f0); mn1 = fminf(mn1, f1); mn2 = fminf(mn2, f2v); mn3 = fminf(mn3, f3);
    e = en;
  }
  // combine the two half-wave partials (lane i <-> lane i+32, same channels)
  sm0 += __shfl_xor(sm0, 32); sm1 += __shfl_xor(sm1, 32);
  sm2 += __shfl_xor(sm2, 32); sm3 += __shfl_xor(sm3, 32);
  mx0 = fmaxf(mx0, __shfl_xor(mx0, 32)); mx1 = fmaxf(mx1, __shfl_xor(mx1, 32));
  mx2 = fmaxf(mx2, __shfl_xor(mx2, 32)); mx3 = fmaxf(mx3, __shfl_xor(mx3, 32));
  mn0 = fminf(mn0, __shfl_xor(mn0, 32)); mn1 = fminf(mn1, __shfl_xor(mn1, 32));
  mn2 = fminf(mn2, __shfl_xor(mn2, 32)); mn3 = fminf(mn3, __shfl_xor(mn3, 32));

  int deg = end - beg;
  float inv = (deg > 0) ? (1.0f / (float)deg) : 0.0f;
  if (deg == 0) {
    mx0 = mx1 = mx2 = mx3 = 0.f;
    mn0 = mn1 = mn2 = mn3 = 0.f;
  }
  unsigned short* row = s + (size_t)wid * 512;
  if (half == 0) {
    ushort4 m4; m4.x = f2bf(sm0 * inv); m4.y = f2bf(sm1 * inv); m4.z = f2bf(sm2 * inv); m4.w = f2bf(sm3 * inv);
    *(ushort4*)(row + 4 * l5) = m4;
    ushort4 x4; x4.x = f2bf(mx0); x4.y = f2bf(mx1); x4.z = f2bf(mx2); x4.w = f2bf(mx3);
    *(ushort4*)(row + 128 + 4 * l5) = x4;
  } else {
    ushort4 n4; n4.x = f2bf(mn0); n4.y = f2bf(mn1); n4.z = f2bf(mn2); n4.w = f2bf(mn3);
    *(ushort4*)(row + 256 + 4 * l5) = n4;
    ushort4 s4; s4.x = f2bf(sm0); s4.y = f2bf(sm1); s4.z = f2bf(sm2); s4.w = f2bf(sm3);
    *(ushort4*)(row + 384 + 4 * l5) = s4;
  }
}

// B matrix [n=128][k=1152] bf16: k<128 -> W1_r1+W1_r2 ; 128..640 -> W2_r1 ; rest W2_r2
__global__ void buildB_kernel(const float* __restrict__ W1a, const float* __restrict__ W2a,
                              const float* __restrict__ W1b, const float* __restrict__ W2b,
                              unsigned short* __restrict__ Bm) {
  int i = blockIdx.x * blockDim.x + threadIdx.x;
  if (i >= 128 * 1152) return;
  int n = i / 1152, k = i % 1152;
  float v;
  if (k < 128)      v = W1a[n * 128 + k] + W1b[n * 128 + k];
  else if (k < 640) v = W2a[n * 512 + (k - 128)];
  else              v = W2b[n * 512 + (k - 640)];
  Bm[i] = f2bf(v);
}

__device__ __forceinline__ void gload16(void* lds, const void* g) {
  __builtin_amdgcn_global_load_lds(
      (const __attribute__((address_space(1))) char*)g,
      (__attribute__((address_space(3))) char*)lds, 16, 0, 0);
}

// One block: 64 rows x 128 cols (full N). K=1152 over {xb, s1, s2}. 4 waves 2x2,
// each wave 32 rows x 64 cols (2x4 frags of 16x16). Fused 0.5*+relu+LayerNorm.
__global__ __launch_bounds__(256) void gemm_ln_kernel(
    const unsigned short* __restrict__ xb, const unsigned short* __restrict__ s1,
    const unsigned short* __restrict__ s2, const unsigned short* __restrict__ Bm,
    const float* __restrict__ gamma, const float* __restrict__ beta,
    float* __restrict__ out) {
  __shared__ __align__(16) unsigned short As[64 * 64];   // [row][k]
  __shared__ __align__(16) unsigned short Bs[128 * 64];  // [n][k]
  __shared__ float rsum[64][2];
  __shared__ float rsq[64][2];

  const int t = threadIdx.x;
  const int lane = t & 63;
  const int wid = t >> 6;
  const int wr = wid >> 1, wc = wid & 1;
  const int m0 = blockIdx.x * 64;

  f32x4 acc[2][4];
  #pragma unroll
  for (int i = 0; i < 2; ++i)
    #pragma unroll
    for (int j = 0; j < 4; ++j) acc[i][j] = {0.f, 0.f, 0.f, 0.f};

  for (int kt = 0; kt < 18; ++kt) {
    const unsigned short* aptr; int astride, kloc;
    if (kt < 2)       { aptr = xb; astride = 128; kloc = kt * 64; }
    else if (kt < 10) { aptr = s1; astride = 512; kloc = (kt - 2) * 64; }
    else              { aptr = s2; astride = 512; kloc = (kt - 10) * 64; }

    #pragma unroll
    for (int i = 0; i < 2; ++i) {                 // A: 512 x 16B chunks
      int chunk = i * 256 + t;
      int r = chunk >> 3, c8 = chunk & 7;
      gload16(As + chunk * 8, aptr + (size_t)(m0 + r) * astride + kloc + c8 * 8);
    }
    #pragma unroll
    for (int i = 0; i < 4; ++i) {                 // B: 1024 x 16B chunks
      int chunk = i * 256 + t;
      int r = chunk >> 3, c8 = chunk & 7;
      gload16(Bs + chunk * 8, Bm + (size_t)r * 1152 + kt * 64 + c8 * 8);
    }
    __syncthreads();

    #pragma unroll
    for (int kk = 0; kk < 2; ++kk) {
      bf16x8 a[2], b[4];
      int ko = kk * 32 + ((lane >> 4) << 3);
      #pragma unroll
      for (int mf = 0; mf < 2; ++mf) {
        int row = wr * 32 + mf * 16 + (lane & 15);
        a[mf] = *(const bf16x8*)(As + row * 64 + ko);
      }
      #pragma unroll
      for (int nf = 0; nf < 4; ++nf) {
        int n = wc * 64 + nf * 16 + (lane & 15);
        b[nf] = *(const bf16x8*)(Bs + n * 64 + ko);
      }
      #pragma unroll
      for (int mf = 0; mf < 2; ++mf)
        #pragma unroll
        for (int nf = 0; nf < 4; ++nf)
          acc[mf][nf] = __builtin_amdgcn_mfma_f32_16x16x32_bf16(a[mf], b[nf], acc[mf][nf], 0, 0, 0);
    }
    __syncthreads();
  }

  // epilogue: h = relu(0.5*acc); LayerNorm over 128 cols per row
  float g[4], bta[4];
  #pragma unroll
  for (int nf = 0; nf < 4; ++nf) {
    int n = wc * 64 + nf * 16 + (lane & 15);
    g[nf] = gamma[n]; bta[nf] = beta[n];
  }

  #pragma unroll
  for (int mf = 0; mf < 2; ++mf) {
    #pragma unroll
    for (int r = 0; r < 4; ++r) {
      float ps = 0.f, pq = 0.f;
      #pragma unroll
      for (int nf = 0; nf < 4; ++nf) {
        float v = fmaxf(0.5f * acc[mf][nf][r], 0.0f);
        acc[mf][nf][r] = v;
        ps += v; pq += v * v;
      }
      #pragma unroll
      for (int d = 1; d < 16; d <<= 1) {
        ps += __shfl_xor(ps, d);
        pq += __shfl_xor(pq, d);
      }
      if ((lane & 15) == 0) {
        int m = wr * 32 + mf * 16 + ((lane >> 4) << 2) + r;
        rsum[m][wc] = ps;
        rsq[m][wc] = pq;
      }
    }
  }
  __syncthreads();

  #pragma unroll
  for (int mf = 0; mf < 2; ++mf) {
    #pragma unroll
    for (int r = 0; r < 4; ++r) {
      int m = wr * 32 + mf * 16 + ((lane >> 4) << 2) + r;
      float sum = rsum[m][0] + rsum[m][1];
      float sq  = rsq[m][0] + rsq[m][1];
      float mu = sum * (1.0f / 128.0f);
      float var = fmaxf(sq * (1.0f / 128.0f) - mu * mu, 0.0f);
      float rstd = rsqrtf(var + 1e-5f);
      int mg = m0 + m;
      if (mg < N_NODES) {
        #pragma unroll
        for (int nf = 0; nf < 4; ++nf) {
          int n = wc * 64 + nf * 16 + (lane & 15);
          out[(size_t)mg * 128 + n] = (acc[mf][nf][r] - mu) * rstd * g[nf] + bta[nf];
        }
      }
    }
  }
}

extern "C" void kernel_launch(void* const* d_in, const int* in_sizes, int n_in,
                              void* d_out, int out_size, void* d_ws, size_t ws_size,
                              hipStream_t stream) {
  const float* x    = (const float*)d_in[0];
  const int*   ei1  = (const int*)d_in[1];
  const int*   ei2  = (const int*)d_in[2];
  const float* W1a  = (const float*)d_in[3];
  const float* W2a  = (const float*)d_in[4];
  const float* W1b  = (const float*)d_in[5];
  const float* W2b  = (const float*)d_in[6];
  const float* gamma = (const float*)d_in[7];
  const float* beta  = (const float*)d_in[8];
  float* out = (float*)d_out;

  char* w = (char*)d_ws;
  auto alloc = [&](size_t b) { char* p = w; w += (b + 255) & ~(size_t)255; return p; };
  int* cnt1 = (int*)alloc((size_t)N_NODES * 4);
  int* cnt2 = (int*)alloc((size_t)N_NODES * 4);
  int* off1 = (int*)alloc((size_t)(N_NODES + 1) * 4);
  int* off2 = (int*)alloc((size_t)(N_NODES + 1) * 4);
  int* cur1 = (int*)alloc((size_t)N_NODES * 4);
  int* cur2 = (int*)alloc((size_t)N_NODES * 4);
  int* csr1 = (int*)alloc((size_t)N_EDGES * 4);
  int* csr2 = (int*)alloc((size_t)N_EDGES * 4);
  int* bsum = (int*)alloc((size_t)2 * NCHUNK * 4);
  int* bbase = (int*)alloc((size_t)2 * NCHUNK * 4);
  unsigned short* xb = (unsigned short*)alloc((size_t)M_PAD * 128 * 2);
  unsigned short* s1 = (unsigned short*)alloc((size_t)M_PAD * 512 * 2);
  unsigned short* s2 = (unsigned short*)alloc((size_t)M_PAD * 512 * 2);
  unsigned short* Bm = (unsigned short*)alloc((size_t)128 * 1152 * 2);

  hipMemsetAsync(cnt1, 0, (size_t)N_NODES * 4, stream);
  hipMemsetAsync(cnt2, 0, (size_t)N_NODES * 4, stream);
  hist2_kernel<<<dim3(2344, 2), 256, 0, stream>>>(ei1 + N_EDGES, ei2 + N_EDGES, cnt1, cnt2, N_EDGES);
  scan_blocks_kernel<<<dim3(NCHUNK, 2), 256, 0, stream>>>(cnt1, cnt2, off1, off2, bsum, N_NODES);
  scan_mid_kernel<<<2, 256, 0, stream>>>(bsum, bbase, off1, off2, NCHUNK, N_NODES);
  scan_add_kernel<<<dim3(NCHUNK, 2), 256, 0, stream>>>(bbase, off1, off2, cur1, cur2, N_NODES);
  fill2_kernel<<<dim3(2344, 2), 256, 0, stream>>>(ei1, ei2, cur1, cur2, csr1, csr2, N_EDGES);
  convx_kernel<<<12500, 256, 0, stream>>>(x, xb);
  aggregate_kernel<<<dim3(12500, 2), 256, 0, stream>>>(xb, csr1, off1, s1, csr2, off2, s2);
  buildB_kernel<<<576, 256, 0, stream>>>(W1a, W2a, W1b, W2b, Bm);
  gemm_ln_kernel<<<782, 256, 0, stream>>>(xb, s1, s2, Bm, gamma, beta, out);
}

// Round 5
// 250.616 us; speedup vs baseline: 1.6250x; 1.0308x over previous
//
#include <hip/hip_runtime.h>
#include <stdint.h>

#define N_NODES 50000
#define N_EDGES 600000
#define M_PAD   50048   // padded rows for GEMM tiles (multiple of 64)
#define NCHUNK  196     // ceil(50000/256)
#define NPASS   8
#define PASS_SZ 6250    // N_NODES / NPASS

typedef __bf16 bf16x8 __attribute__((ext_vector_type(8)));
typedef float  f32x4  __attribute__((ext_vector_type(4)));

__device__ __forceinline__ unsigned short f2bf(float f) {
  union { float f; unsigned u; } v; v.f = f;
  unsigned r = v.u + 0x7FFF + ((v.u >> 16) & 1);  // round-to-nearest-even
  return (unsigned short)(r >> 16);
}

__global__ void hist2_kernel(const int* __restrict__ d1, const int* __restrict__ d2,
                             int* __restrict__ c1, int* __restrict__ c2, int e) {
  const int* dst = blockIdx.y ? d2 : d1;
  int* cnt = blockIdx.y ? c2 : c1;
  int i = blockIdx.x * blockDim.x + threadIdx.x;
  if (i < e) atomicAdd(&cnt[dst[i]], 1);
}

// Pass 1: per-256-chunk exclusive scan (wave shuffle + LDS cross-wave), block sums out.
__global__ void scan_blocks_kernel(const int* __restrict__ cnt1, const int* __restrict__ cnt2,
                                   int* __restrict__ off1, int* __restrict__ off2,
                                   int* __restrict__ bsum, int n) {
  const int* cnt = blockIdx.y ? cnt2 : cnt1;
  int* off = blockIdx.y ? off2 : off1;
  int* bs = bsum + blockIdx.y * NCHUNK;
  int tid = threadIdx.x, lane = tid & 63, wid = tid >> 6;
  int i = blockIdx.x * 256 + tid;
  int v = (i < n) ? cnt[i] : 0;
  int val = v;
  #pragma unroll
  for (int d = 1; d < 64; d <<= 1) {
    int t = __shfl_up(val, d);
    if (lane >= d) val += t;
  }
  __shared__ int ws[4];
  if (lane == 63) ws[wid] = val;
  __syncthreads();
  int wbase = 0;
  #pragma unroll
  for (int w = 0; w < 3; ++w) wbase += (w < wid) ? ws[w] : 0;
  int inc = wbase + val;
  if (i < n) off[i] = inc - v;     // chunk-local exclusive
  if (tid == 255) bs[blockIdx.x] = inc;
}

// Pass 2: scan the 196 block sums (one block per relation); also writes off[n].
__global__ void scan_mid_kernel(const int* __restrict__ bsum, int* __restrict__ bbase,
                                int* __restrict__ off1, int* __restrict__ off2, int nb, int n) {
  int rel = blockIdx.x;
  const int* bs = bsum + rel * NCHUNK;
  int* bb = bbase + rel * NCHUNK;
  int tid = threadIdx.x, lane = tid & 63, wid = tid >> 6;
  int v = (tid < nb) ? bs[tid] : 0;
  int val = v;
  #pragma unroll
  for (int d = 1; d < 64; d <<= 1) {
    int t = __shfl_up(val, d);
    if (lane >= d) val += t;
  }
  __shared__ int ws[4];
  if (lane == 63) ws[wid] = val;
  __syncthreads();
  int wbase = 0;
  #pragma unroll
  for (int w = 0; w < 3; ++w) wbase += (w < wid) ? ws[w] : 0;
  int inc = wbase + val;
  if (tid < nb) bb[tid] = inc - v;
  if (tid == 255) { int* off = rel ? off2 : off1; off[n] = inc; }
}

// Pass 3: add block bases; produce final off and the cursor copy.
__global__ void scan_add_kernel(const int* __restrict__ bbase,
                                int* __restrict__ off1, int* __restrict__ off2,
                                int* __restrict__ cur1, int* __restrict__ cur2, int n) {
  int* off = blockIdx.y ? off2 : off1;
  int* cur = blockIdx.y ? cur2 : cur1;
  int b = bbase[blockIdx.y * NCHUNK + blockIdx.x];
  int i = blockIdx.x * 256 + threadIdx.x;
  if (i < n) { int o = off[i] + b; off[i] = o; cur[i] = o; }
}

// CSR scatter, dst-range partitioned into NPASS passes so that at any moment
// the whole GPU's atomics+stores target a ~650KB L2-resident region.
__global__ void fill2_kernel(const int* __restrict__ ei1, const int* __restrict__ ei2,
                             int* __restrict__ cur1, int* __restrict__ cur2,
                             int* __restrict__ csr1, int* __restrict__ csr2, int e) {
  const int* ei = blockIdx.y ? ei2 : ei1;
  int* cur = blockIdx.y ? cur2 : cur1;
  int* csr = blockIdx.y ? csr2 : csr1;
  int i = blockIdx.x * blockDim.x + threadIdx.x;
  bool valid = (i < e);
  int d = 0, sr = 0, p = 0;
  if (valid) {
    d = ei[e + i];               // dst row
    sr = ei[i];                  // src row
    p = d / PASS_SZ;
  }
  #pragma unroll 1
  for (int pass = 0; pass < NPASS; ++pass) {
    if (valid && p == pass) {
      int pos = atomicAdd(&cur[d], 1);
      csr[pos] = sr;
    }
    __syncthreads();             // uniform: no early returns above
  }
}

__global__ void convx_kernel(const float* __restrict__ x, unsigned short* __restrict__ xb) {
  int i = blockIdx.x * blockDim.x + threadIdx.x;  // float2 index
  if (i < N_NODES * 64) {
    float2 v = ((const float2*)x)[i];
    ((ushort2*)xb)[i] = make_ushort2(f2bf(v.x), f2bf(v.y));
  }
}

// One wave per node. Quarter-wave per edge: quarter q handles edges e=beg+q,+4,...;
// lane (q,p) owns channels 8p..8p+7 (uint4 = 16B of bf16 row). Unpack via the
// dword trick (lo = u<<16, hi = u & 0xFFFF0000): 1 VALU inst per channel.
// Combine quarters via shfl_xor(16)+shfl_xor(32); quarter q writes reducer q
// (mean|max|min|sum), one 16B store per lane. grid.y selects relation.
__global__ void aggregate_kernel(const unsigned short* __restrict__ xb,
                                 const int* __restrict__ csr1, const int* __restrict__ off1,
                                 unsigned short* __restrict__ sa,
                                 const int* __restrict__ csr2, const int* __restrict__ off2,
                                 unsigned short* __restrict__ sb) {
  const int* csr = blockIdx.y ? csr2 : csr1;
  const int* off = blockIdx.y ? off2 : off1;
  unsigned short* s = blockIdx.y ? sb : sa;
  int wid = blockIdx.x * 4 + (threadIdx.x >> 6);
  int lane = threadIdx.x & 63;
  if (wid >= N_NODES) return;
  int beg = off[wid], end = off[wid + 1];
  int q = lane >> 4, p = lane & 15;

  float sm[8], mx[8], mn[8];
  #pragma unroll
  for (int j = 0; j < 8; ++j) { sm[j] = 0.f; mx[j] = -3.0e38f; mn[j] = 3.0e38f; }

  int e = beg + q;
  int sr_next = (e < end) ? csr[e] : 0;
  while (e < end) {
    int sr = sr_next;
    int en = e + 4;
    if (en < end) sr_next = csr[en];
    uint4 v = *(const uint4*)(xb + (size_t)sr * 128 + 8 * p);   // 8 channels, 16B
    #pragma unroll
    for (int j = 0; j < 4; ++j) {
      unsigned d = (j == 0) ? v.x : (j == 1) ? v.y : (j == 2) ? v.z : v.w;
      float lo = __uint_as_float(d << 16);
      float hi = __uint_as_float(d & 0xFFFF0000u);
      sm[2*j]   += lo;                sm[2*j+1] += hi;
      mx[2*j]   = fmaxf(mx[2*j], lo); mx[2*j+1] = fmaxf(mx[2*j+1], hi);
      mn[2*j]   = fminf(mn[2*j], lo); mn[2*j+1] = fminf(mn[2*j+1], hi);
    }
    e = en;
  }
  // combine the 4 quarter-wave partials (same channels live at lanes p, p+16, p+32, p+48)
  #pragma unroll
  for (int j = 0; j < 8; ++j) {
    sm[j] += __shfl_xor(sm[j], 16);
    mx[j] = fmaxf(mx[j], __shfl_xor(mx[j], 16));
    mn[j] = fminf(mn[j], __shfl_xor(mn[j], 16));
  }
  #pragma unroll
  for (int j = 0; j < 8; ++j) {
    sm[j] += __shfl_xor(sm[j], 32);
    mx[j] = fmaxf(mx[j], __shfl_xor(mx[j], 32));
    mn[j] = fminf(mn[j], __shfl_xor(mn[j], 32));
  }

  int deg = end - beg;
  float inv = (deg > 0) ? (1.0f / (float)deg) : 0.0f;
  if (deg == 0) {
    #pragma unroll
    for (int j = 0; j < 8; ++j) { mx[j] = 0.f; mn[j] = 0.f; }
  }
  // quarter q emits reducer q: 0=mean 1=max 2=min 3=sum
  unsigned dw[4];
  #pragma unroll
  for (int j = 0; j < 4; ++j) {
    float a = (q == 0) ? sm[2*j] * inv : (q == 1) ? mx[2*j] : (q == 2) ? mn[2*j] : sm[2*j];
    float b = (q == 0) ? sm[2*j+1] * inv : (q == 1) ? mx[2*j+1] : (q == 2) ? mn[2*j+1] : sm[2*j+1];
    dw[j] = (unsigned)f2bf(a) | ((unsigned)f2bf(b) << 16);
  }
  uint4 outv = make_uint4(dw[0], dw[1], dw[2], dw[3]);
  *(uint4*)(s + (size_t)wid * 512 + q * 128 + 8 * p) = outv;
}

// B matrix [n=128][k=1152] bf16: k<128 -> W1_r1+W1_r2 ; 128..640 -> W2_r1 ; rest W2_r2
__global__ void buildB_kernel(const float* __restrict__ W1a, const float* __restrict__ W2a,
                              const float* __restrict__ W1b, const float* __restrict__ W2b,
                              unsigned short* __restrict__ Bm) {
  int i = blockIdx.x * blockDim.x + threadIdx.x;
  if (i >= 128 * 1152) return;
  int n = i / 1152, k = i % 1152;
  float v;
  if (k < 128)      v = W1a[n * 128 + k] + W1b[n * 128 + k];
  else if (k < 640) v = W2a[n * 512 + (k - 128)];
  else              v = W2b[n * 512 + (k - 640)];
  Bm[i] = f2bf(v);
}

__device__ __forceinline__ void gload16(void* lds, const void* g) {
  __builtin_amdgcn_global_load_lds(
      (const __attribute__((address_space(1))) char*)g,
      (__attribute__((address_space(3))) char*)lds, 16, 0, 0);
}

// One block: 64 rows x 128 cols (full N). K=1152 over {xb, s1, s2}. 4 waves 2x2,
// each wave 32 rows x 64 cols (2x4 frags of 16x16). Fused 0.5*+relu+LayerNorm.
__global__ __launch_bounds__(256) void gemm_ln_kernel(
    const unsigned short* __restrict__ xb, const unsigned short* __restrict__ s1,
    const unsigned short* __restrict__ s2, const unsigned short* __restrict__ Bm,
    const float* __restrict__ gamma, const float* __restrict__ beta,
    float* __restrict__ out) {
  __shared__ __align__(16) unsigned short As[64 * 64];   // [row][k]
  __shared__ __align__(16) unsigned short Bs[128 * 64];  // [n][k]
  __shared__ float rsum[64][2];
  __shared__ float rsq[64][2];

  const int t = threadIdx.x;
  const int lane = t & 63;
  const int wid = t >> 6;
  const int wr = wid >> 1, wc = wid & 1;
  const int m0 = blockIdx.x * 64;

  f32x4 acc[2][4];
  #pragma unroll
  for (int i = 0; i < 2; ++i)
    #pragma unroll
    for (int j = 0; j < 4; ++j) acc[i][j] = {0.f, 0.f, 0.f, 0.f};

  for (int kt = 0; kt < 18; ++kt) {
    const unsigned short* aptr; int astride, kloc;
    if (kt < 2)       { aptr = xb; astride = 128; kloc = kt * 64; }
    else if (kt < 10) { aptr = s1; astride = 512; kloc = (kt - 2) * 64; }
    else              { aptr = s2; astride = 512; kloc = (kt - 10) * 64; }

    #pragma unroll
    for (int i = 0; i < 2; ++i) {                 // A: 512 x 16B chunks
      int chunk = i * 256 + t;
      int r = chunk >> 3, c8 = chunk & 7;
      gload16(As + chunk * 8, aptr + (size_t)(m0 + r) * astride + kloc + c8 * 8);
    }
    #pragma unroll
    for (int i = 0; i < 4; ++i) {                 // B: 1024 x 16B chunks
      int chunk = i * 256 + t;
      int r = chunk >> 3, c8 = chunk & 7;
      gload16(Bs + chunk * 8, Bm + (size_t)r * 1152 + kt * 64 + c8 * 8);
    }
    __syncthreads();

    #pragma unroll
    for (int kk = 0; kk < 2; ++kk) {
      bf16x8 a[2], b[4];
      int ko = kk * 32 + ((lane >> 4) << 3);
      #pragma unroll
      for (int mf = 0; mf < 2; ++mf) {
        int row = wr * 32 + mf * 16 + (lane & 15);
        a[mf] = *(const bf16x8*)(As + row * 64 + ko);
      }
      #pragma unroll
      for (int nf = 0; nf < 4; ++nf) {
        int n = wc * 64 + nf * 16 + (lane & 15);
        b[nf] = *(const bf16x8*)(Bs + n * 64 + ko);
      }
      #pragma unroll
      for (int mf = 0; mf < 2; ++mf)
        #pragma unroll
        for (int nf = 0; nf < 4; ++nf)
          acc[mf][nf] = __builtin_amdgcn_mfma_f32_16x16x32_bf16(a[mf], b[nf], acc[mf][nf], 0, 0, 0);
    }
    __syncthreads();
  }

  // epilogue: h = relu(0.5*acc); LayerNorm over 128 cols per row
  float g[4], bta[4];
  #pragma unroll
  for (int nf = 0; nf < 4; ++nf) {
    int n = wc * 64 + nf * 16 + (lane & 15);
    g[nf] = gamma[n]; bta[nf] = beta[n];
  }

  #pragma unroll
  for (int mf = 0; mf < 2; ++mf) {
    #pragma unroll
    for (int r = 0; r < 4; ++r) {
      float ps = 0.f, pq = 0.f;
      #pragma unroll
      for (int nf = 0; nf < 4; ++nf) {
        float v = fmaxf(0.5f * acc[mf][nf][r], 0.0f);
        acc[mf][nf][r] = v;
        ps += v; pq += v * v;
      }
      #pragma unroll
      for (int d = 1; d < 16; d <<= 1) {
        ps += __shfl_xor(ps, d);
        pq += __shfl_xor(pq, d);
      }
      if ((lane & 15) == 0) {
        int m = wr * 32 + mf * 16 + ((lane >> 4) << 2) + r;
        rsum[m][wc] = ps;
        rsq[m][wc] = pq;
      }
    }
  }
  __syncthreads();

  #pragma unroll
  for (int mf = 0; mf < 2; ++mf) {
    #pragma unroll
    for (int r = 0; r < 4; ++r) {
      int m = wr * 32 + mf * 16 + ((lane >> 4) << 2) + r;
      float sum = rsum[m][0] + rsum[m][1];
      float sq  = rsq[m][0] + rsq[m][1];
      float mu = sum * (1.0f / 128.0f);
      float var = fmaxf(sq * (1.0f / 128.0f) - mu * mu, 0.0f);
      float rstd = rsqrtf(var + 1e-5f);
      int mg = m0 + m;
      if (mg < N_NODES) {
        #pragma unroll
        for (int nf = 0; nf < 4; ++nf) {
          int n = wc * 64 + nf * 16 + (lane & 15);
          out[(size_t)mg * 128 + n] = (acc[mf][nf][r] - mu) * rstd * g[nf] + bta[nf];
        }
      }
    }
  }
}

extern "C" void kernel_launch(void* const* d_in, const int* in_sizes, int n_in,
                              void* d_out, int out_size, void* d_ws, size_t ws_size,
                              hipStream_t stream) {
  const float* x    = (const float*)d_in[0];
  const int*   ei1  = (const int*)d_in[1];
  const int*   ei2  = (const int*)d_in[2];
  const float* W1a  = (const float*)d_in[3];
  const float* W2a  = (const float*)d_in[4];
  const float* W1b  = (const float*)d_in[5];
  const float* W2b  = (const float*)d_in[6];
  const float* gamma = (const float*)d_in[7];
  const float* beta  = (const float*)d_in[8];
  float* out = (float*)d_out;

  char* w = (char*)d_ws;
  auto alloc = [&](size_t b) { char* p = w; w += (b + 255) & ~(size_t)255; return p; };
  int* cnt1 = (int*)alloc((size_t)N_NODES * 4);
  int* cnt2 = (int*)alloc((size_t)N_NODES * 4);
  int* off1 = (int*)alloc((size_t)(N_NODES + 1) * 4);
  int* off2 = (int*)alloc((size_t)(N_NODES + 1) * 4);
  int* cur1 = (int*)alloc((size_t)N_NODES * 4);
  int* cur2 = (int*)alloc((size_t)N_NODES * 4);
  int* csr1 = (int*)alloc((size_t)N_EDGES * 4);
  int* csr2 = (int*)alloc((size_t)N_EDGES * 4);
  int* bsum = (int*)alloc((size_t)2 * NCHUNK * 4);
  int* bbase = (int*)alloc((size_t)2 * NCHUNK * 4);
  unsigned short* xb = (unsigned short*)alloc((size_t)M_PAD * 128 * 2);
  unsigned short* s1 = (unsigned short*)alloc((size_t)M_PAD * 512 * 2);
  unsigned short* s2 = (unsigned short*)alloc((size_t)M_PAD * 512 * 2);
  unsigned short* Bm = (unsigned short*)alloc((size_t)128 * 1152 * 2);

  hipMemsetAsync(cnt1, 0, (size_t)N_NODES * 4, stream);
  hipMemsetAsync(cnt2, 0, (size_t)N_NODES * 4, stream);
  hist2_kernel<<<dim3(2344, 2), 256, 0, stream>>>(ei1 + N_EDGES, ei2 + N_EDGES, cnt1, cnt2, N_EDGES);
  scan_blocks_kernel<<<dim3(NCHUNK, 2), 256, 0, stream>>>(cnt1, cnt2, off1, off2, bsum, N_NODES);
  scan_mid_kernel<<<2, 256, 0, stream>>>(bsum, bbase, off1, off2, NCHUNK, N_NODES);
  scan_add_kernel<<<dim3(NCHUNK, 2), 256, 0, stream>>>(bbase, off1, off2, cur1, cur2, N_NODES);
  fill2_kernel<<<dim3(2344, 2), 256, 0, stream>>>(ei1, ei2, cur1, cur2, csr1, csr2, N_EDGES);
  convx_kernel<<<12500, 256, 0, stream>>>(x, xb);
  aggregate_kernel<<<dim3(12500, 2), 256, 0, stream>>>(xb, csr1, off1, s1, csr2, off2, s2);
  buildB_kernel<<<576, 256, 0, stream>>>(W1a, W2a, W1b, W2b, Bm);
  gemm_ln_kernel<<<782, 256, 0, stream>>>(xb, s1, s2, Bm, gamma, beta, out);
}